// Round 10
// baseline (188.990 us; speedup 1.0000x reference)
//
#include <hip/hip_runtime.h>
#include <hip/hip_bf16.h>

// Problem dims
#define BROWS 8192
#define IDIM 256
#define HDIM 512
#define KCAT 768    // I + H
#define G4 2048     // 4*H

typedef __bf16 bf16_t;
typedef bf16_t bf16x8 __attribute__((ext_vector_type(8)));
typedef float f32x4 __attribute__((ext_vector_type(4)));

__device__ __forceinline__ f32x4 mfma16(bf16x8 a, bf16x8 b, f32x4 c) {
    return __builtin_amdgcn_mfma_f32_16x16x32_bf16(a, b, c, 0, 0, 0);
}

__device__ __forceinline__ ushort f2bf(float f) {
    union { float f; unsigned u; } v; v.f = f;
    unsigned u = v.u;
    unsigned r = (u + 0x7fffu + ((u >> 16) & 1u)) >> 16;  // RNE, inputs finite
    return (ushort)r;
}

__device__ __forceinline__ float bf2f(ushort u) {
    union { unsigned u; float f; } v; v.u = (unsigned)u << 16; return v.f;
}

__device__ __forceinline__ float sigmoidf_(float x) {
    return 1.f / (1.f + __expf(-x));
}
__device__ __forceinline__ float tanhf_(float x) {
    return 1.f - 2.f / (__expf(2.f * x) + 1.f);   // safe at +/-inf
}

// async global -> LDS, 16 bytes per lane (lds dest: wave-uniform base + lane*16)
typedef __attribute__((address_space(1))) const unsigned gas_u32;
typedef __attribute__((address_space(3))) unsigned las_u32;
__device__ __forceinline__ void gld_lds16(const void* g, void* l) {
    __builtin_amdgcn_global_load_lds((gas_u32*)g, (las_u32*)l, 16, 0, 0);
}

// ---------------- prep: fp32 -> bf16 packing (float4 vectorized) ----------------
__global__ void __launch_bounds__(256) prep_kernel(
        const float* __restrict__ x, const float* __restrict__ h,
        const float* __restrict__ aw0, const float* __restrict__ aw1,
        const float* __restrict__ w_ih, const float* __restrict__ w_hh,
        const float* __restrict__ ow0,
        ushort* __restrict__ xh, ushort* __restrict__ baw0,
        ushort* __restrict__ baw1, ushort* __restrict__ wcat,
        ushort* __restrict__ bow0) {
    int idx = (blockIdx.x * 256 + threadIdx.x) * 4;
    const int N_XH = BROWS * KCAT;      // 6291456
    const int N_AW0 = IDIM * KCAT;      // 196608
    const int N_AW1 = IDIM * IDIM;      // 65536
    const int N_WCAT = G4 * KCAT;       // 1572864
    const int N_OW0 = HDIM * HDIM;      // 262144
    float4 v;
    ushort* dst;
    if (idx < N_XH) {
        int b = idx / KCAT, k = idx - b * KCAT;
        v = (k < IDIM) ? *(const float4*)&x[b * IDIM + k]
                       : *(const float4*)&h[b * HDIM + (k - IDIM)];
        dst = &xh[idx];
    } else if ((idx -= N_XH) < N_AW0) {
        v = *(const float4*)&aw0[idx]; dst = &baw0[idx];
    } else if ((idx -= N_AW0) < N_AW1) {
        v = *(const float4*)&aw1[idx]; dst = &baw1[idx];
    } else if ((idx -= N_AW1) < N_WCAT) {
        int o = idx / KCAT, k = idx - o * KCAT;
        v = (k < IDIM) ? *(const float4*)&w_ih[o * IDIM + k]
                       : *(const float4*)&w_hh[o * HDIM + (k - IDIM)];
        dst = &wcat[idx];
    } else if ((idx -= N_WCAT) < N_OW0) {
        v = *(const float4*)&ow0[idx]; dst = &bow0[idx];
    } else {
        return;
    }
    ushort4 o4 = { f2bf(v.x), f2bf(v.y), f2bf(v.z), f2bf(v.w) };
    *(ushort4*)dst = o4;
}

// ---------------- staged GEMM (small GEMMs; R8-proven) ----------------
template<int RELU_BF16, int NFRAG>
__global__ void __launch_bounds__(256) staged_gemm(
        const ushort* __restrict__ A, const ushort* __restrict__ W,
        const float* __restrict__ bias, void* __restrict__ outp,
        int Kdim, int out_ld) {
    __shared__ ushort As[2][4096];
    __shared__ ushort Ws[2][NFRAG * 1024];
    const int tid = threadIdx.x;
    const int lane = tid & 63, wave = tid >> 6;
    const int wm = wave >> 1, wn = wave & 1;
    const int r = lane & 15, g = lane >> 4;
    const int rb = blockIdx.x & 63, cb = blockIdx.x >> 6;
    const int row0 = rb * 128, col0 = cb * (NFRAG * 32);
    const int s_row = tid >> 2;
    const int s_sw = ((tid & 3) ^ ((s_row >> 1) & 3)) * 8;

    const ushort* aBase = A + (size_t)(row0 + s_row) * Kdim + s_sw;
    const ushort* wBase = W + (size_t)(col0 + s_row) * Kdim + s_sw;
    const int step64 = 64 * Kdim;
    const int rsw = (g ^ ((r >> 1) & 3)) * 8;

    f32x4 acc[4][NFRAG] = {};

    auto stage = [&](int buf, int t) {
        const int o = t * 32;
        gld_lds16(aBase + o,          &As[buf][wave * 512]);
        gld_lds16(aBase + o + step64, &As[buf][2048 + wave * 512]);
        gld_lds16(wBase + o,          &Ws[buf][wave * 512]);
        if (NFRAG == 4)
            gld_lds16(wBase + o + step64, &Ws[buf][2048 + wave * 512]);
    };
    auto compute = [&](int buf) {
        bf16x8 af[4], wf[NFRAG];
#pragma unroll
        for (int t = 0; t < 4; t++)
            af[t] = *(const bf16x8*)&As[buf][(wm * 4 + t) * 512 + r * 32 + rsw];
#pragma unroll
        for (int t = 0; t < NFRAG; t++)
            wf[t] = *(const bf16x8*)&Ws[buf][(wn * NFRAG + t) * 512 + r * 32 + rsw];
#pragma unroll
        for (int m = 0; m < 4; m++)
#pragma unroll
            for (int n = 0; n < NFRAG; n++)
                acc[m][n] = mfma16(af[m], wf[n], acc[m][n]);
    };

    stage(0, 0);
    __syncthreads();
    const int NT = Kdim >> 5;
    int cur = 0;
    for (int t = 0; t < NT - 1; t++) {
        stage(cur ^ 1, t + 1);
        compute(cur);
        __syncthreads();
        cur ^= 1;
    }
    compute(cur);

#pragma unroll
    for (int n = 0; n < NFRAG; n++) {
        int col = col0 + wn * (NFRAG * 16) + n * 16 + r;
        float bv = bias[col];
#pragma unroll
        for (int m = 0; m < 4; m++) {
            int rbase = row0 + wm * 64 + m * 16 + g * 4;
#pragma unroll
            for (int reg = 0; reg < 4; reg++) {
                float v = acc[m][n][reg] + bv;
                if (RELU_BF16) {
                    v = v > 0.f ? v : 0.f;
                    ((ushort*)outp)[(size_t)(rbase + reg) * out_ld + col] = f2bf(v);
                } else {
                    ((float*)outp)[(size_t)(rbase + reg) * out_ld + col] = v;
                }
            }
        }
    }
}

// ---------------- rowwise softmax + attn out + x_att into xh ----------------
__global__ void __launch_bounds__(256) attn_softmax(
        const float* __restrict__ logits, const float* __restrict__ x,
        float* __restrict__ attn_out, ushort* __restrict__ xh) {
    const int wave = threadIdx.x >> 6, lane = threadIdx.x & 63;
    const int row = blockIdx.x * 4 + wave;
    float v[4];
    float m = -1e30f;
#pragma unroll
    for (int i = 0; i < 4; i++) {
        v[i] = logits[row * IDIM + i * 64 + lane];
        m = fmaxf(m, v[i]);
    }
#pragma unroll
    for (int s = 32; s; s >>= 1) m = fmaxf(m, __shfl_xor(m, s, 64));
    float sum = 0.f;
#pragma unroll
    for (int i = 0; i < 4; i++) { v[i] = __expf(v[i] - m); sum += v[i]; }
#pragma unroll
    for (int s = 32; s; s >>= 1) sum += __shfl_xor(sum, s, 64);
    float inv = 1.f / sum;
#pragma unroll
    for (int i = 0; i < 4; i++) {
        int idx = i * 64 + lane;
        float a = v[i] * inv;
        attn_out[row * IDIM + idx] = a;
        xh[row * KCAT + idx] = f2bf(x[row * IDIM + idx] * a);
    }
}

// ---------------- fused gates GEMM + LSTM epilogue ----------------
// gates = [x_att|h] @ [w_ih|w_hh]^T : M=8192, j=512, 4 gates, K=768.
// BM=BN=256 (256 cols = 4 gates x 64 j), BK=32, 8 waves (2M x 4N),
// wave out 128x64 (acc[8][4]). LDS 64KB (2-slot) -> 2 blocks/CU co-resident:
// halves staged bytes vs 128^2 (A x8, W x32 = 201MB) while keeping R8's
// co-residency-driven staging rate. Simple R8-proven loop:
// stage(t+1) -> compute(t) -> __syncthreads().
// Staging: wave stages subtiles {2w,2w+1} of A and W; lane L covers row
// rr=L>>2 (within subtile s: global row 16s+rr), chunk slot L&3, global
// chunk pre-swizzled c^((rr>>1)&3) (same 64B line -> coalesced).
// Fragment read applies the same XOR -> conflict-free (R8-verified).
// Column mapping puts gate on fragment n: cc = wn*64+n*16+r ->
// gate=(cc>>4)&3 = n, j = j0 + wn*16 + r -> lane-local LSTM epilogue.
// XCD decode: xcd owns 4 rb x 8 cb -> A-panel 1.5MB L2-resident.
__global__ void __launch_bounds__(512, 4) gates_staged(
        const ushort* __restrict__ A, const ushort* __restrict__ W,
        const float* __restrict__ b_ih, const float* __restrict__ b_hh,
        const float* __restrict__ c_in,
        float* __restrict__ h_out, float* __restrict__ c_out,
        ushort* __restrict__ h_bf) {
    __shared__ ushort As[2 * 8192];   // 32KB: 2 bufs x 16 subtiles x 512
    __shared__ ushort Ws[2 * 8192];   // 32KB
    const int tid = threadIdx.x;
    const int lane = tid & 63, wave = tid >> 6;
    const int wm = wave >> 2, wn = wave & 3;    // 2M x 4N
    const int r = lane & 15, g = lane >> 4;
    const int bid = blockIdx.x;                 // 256 blocks
    const int xcd = bid & 7, local = bid >> 3;
    const int rb = xcd * 4 + (local & 3);       // 0..31
    const int cb = local >> 2;                  // 0..7
    const int row0 = rb * 256;
    const int j0 = cb * 64;

    // staging geometry: lane -> (row-in-subtile, chunk)
    const int rl4 = lane >> 2;                  // 0..15
    const int sw4 = ((lane & 3) ^ ((rl4 >> 1) & 3)) * 8;   // pre-swizzled chunk
    const int sA = 2 * wave;                    // this wave's first subtile

    // W row for LDS col cc: gate=(cc>>4)&3, j = j0 + (cc&15) + ((cc>>6)<<4)
    auto wrow = [&](int cc) {
        return ((cc >> 4) & 3) * HDIM + j0 + (cc & 15) + ((cc >> 6) << 4);
    };
    const ushort* aP0 = A + (size_t)(row0 + 16 * sA + rl4) * KCAT + sw4;
    const ushort* aP1 = A + (size_t)(row0 + 16 * (sA + 1) + rl4) * KCAT + sw4;
    const ushort* wP0 = W + (size_t)wrow(16 * sA + rl4) * KCAT + sw4;
    const ushort* wP1 = W + (size_t)wrow(16 * (sA + 1) + rl4) * KCAT + sw4;

    f32x4 acc[8][4] = {};
    const int rsw = (g ^ ((r >> 1) & 3)) * 8;   // read-side swizzle

    auto stage = [&](int buf, int t) {
        const int o = t * 32;
        ushort* la = As + buf * 8192 + sA * 512;
        ushort* lw = Ws + buf * 8192 + sA * 512;
        gld_lds16(aP0 + o, la);
        gld_lds16(aP1 + o, la + 512);
        gld_lds16(wP0 + o, lw);
        gld_lds16(wP1 + o, lw + 512);
    };
    auto compute = [&](int buf) {
        bf16x8 af[8], wf[4];
#pragma unroll
        for (int m = 0; m < 8; m++)
            af[m] = *(const bf16x8*)&As[buf * 8192 + (wm * 8 + m) * 512 + r * 32 + rsw];
#pragma unroll
        for (int n = 0; n < 4; n++)
            wf[n] = *(const bf16x8*)&Ws[buf * 8192 + (wn * 4 + n) * 512 + r * 32 + rsw];
#pragma unroll
        for (int m = 0; m < 8; m++)
#pragma unroll
            for (int n = 0; n < 4; n++)
                acc[m][n] = mfma16(af[m], wf[n], acc[m][n]);
    };

    const int NT = KCAT >> 5;   // 24
    stage(0, 0);
    __syncthreads();
    int cur = 0;
    for (int t = 0; t < NT; t++) {
        if (t + 1 < NT) stage(cur ^ 1, t + 1);   // issue next-tile loads
        compute(cur);                             // hide latency under MFMA
        __syncthreads();                          // t+1 landed; slot t free
        cur ^= 1;
    }

    // LSTM epilogue: lane-local. j fixed per lane; gate = fragment index n.
    const int j = j0 + wn * 16 + r;
    float bb[4];
#pragma unroll
    for (int n = 0; n < 4; n++) bb[n] = b_ih[n * HDIM + j] + b_hh[n * HDIM + j];
#pragma unroll
    for (int m = 0; m < 8; m++) {
        int rbase = row0 + wm * 128 + m * 16 + g * 4;
#pragma unroll
        for (int reg = 0; reg < 4; reg++) {
            int row = rbase + reg;
            float ig = sigmoidf_(acc[m][0][reg] + bb[0]);
            float fg = sigmoidf_(acc[m][1][reg] + bb[1]);
            float gg = tanhf_(acc[m][2][reg] + bb[2]);
            float og = sigmoidf_(acc[m][3][reg] + bb[3]);
            float cn = fg * c_in[(size_t)row * HDIM + j] + ig * gg;
            float hn = og * tanhf_(cn);
            c_out[(size_t)row * HDIM + j] = cn;
            h_out[(size_t)row * HDIM + j] = hn;
            h_bf[(size_t)row * HDIM + j] = f2bf(hn);
        }
    }
}

// ---------------- head GEMV: out = sigmoid(hrelu . ow1 + ob1) ----------------
__global__ void __launch_bounds__(256) head_gemv(
        const ushort* __restrict__ Hrelu, const float* __restrict__ ow1,
        const float* __restrict__ ob1, float* __restrict__ outp) {
    const int wave = threadIdx.x >> 6, lane = threadIdx.x & 63;
    const int row = blockIdx.x * 4 + wave;
    typedef ushort u16x8 __attribute__((ext_vector_type(8)));
    u16x8 hv = *(const u16x8*)&Hrelu[(size_t)row * HDIM + lane * 8];
    float4 w0 = *(const float4*)&ow1[lane * 8];
    float4 w1 = *(const float4*)&ow1[lane * 8 + 4];
    float s = bf2f(hv[0]) * w0.x + bf2f(hv[1]) * w0.y + bf2f(hv[2]) * w0.z +
              bf2f(hv[3]) * w0.w + bf2f(hv[4]) * w1.x + bf2f(hv[5]) * w1.y +
              bf2f(hv[6]) * w1.z + bf2f(hv[7]) * w1.w;
#pragma unroll
    for (int sh = 32; sh; sh >>= 1) s += __shfl_xor(s, sh, 64);
    if (lane == 0) outp[row] = 1.f / (1.f + __expf(-(s + ob1[0])));
}

extern "C" void kernel_launch(void* const* d_in, const int* in_sizes, int n_in,
                              void* d_out, int out_size, void* d_ws, size_t ws_size,
                              hipStream_t stream) {
    const float* x    = (const float*)d_in[0];
    const float* h    = (const float*)d_in[1];
    const float* c    = (const float*)d_in[2];
    const float* aw0  = (const float*)d_in[3];
    const float* ab0  = (const float*)d_in[4];
    const float* aw1  = (const float*)d_in[5];
    const float* ab1  = (const float*)d_in[6];
    const float* w_ih = (const float*)d_in[7];
    const float* b_ih = (const float*)d_in[8];
    const float* w_hh = (const float*)d_in[9];
    const float* b_hh = (const float*)d_in[10];
    const float* ow0  = (const float*)d_in[11];
    const float* ob0  = (const float*)d_in[12];
    const float* ow1  = (const float*)d_in[13];
    const float* ob1  = (const float*)d_in[14];

    char* ws = (char*)d_ws;
    ushort* xh     = (ushort*)(ws + 0);           // 8192*768*2  = 12582912
    ushort* a0     = (ushort*)(ws + 12582912);    // 8192*256*2  = 4194304
    float*  logits = (float*) (ws + 16777216);    // 8192*256*4  = 8388608
    ushort* hrelu  = (ushort*)(ws + 16777216);    // aliases logits (dead after softmax)
    ushort* hbf    = (ushort*)(ws + 25165824);    // 8192*512*2  = 8388608
    ushort* baw0   = (ushort*)(ws + 33554432);    // 256*768*2   = 393216
    ushort* baw1   = (ushort*)(ws + 33947648);    // 256*256*2   = 131072
    ushort* wcat   = (ushort*)(ws + 34078720);    // 2048*768*2  = 3145728
    ushort* bow0   = (ushort*)(ws + 37224448);    // 512*512*2   = 524288

    float* outv    = (float*)d_out;               // [8192]
    float* h_out   = outv + 8192;                 // [8192,512]
    float* c_out   = outv + 4202496;              // [8192,512]
    float* attn_o  = outv + 8396800;              // [8192,256]

    prep_kernel<<<8192, 256, 0, stream>>>(x, h, aw0, aw1, w_ih, w_hh, ow0,
                                          xh, baw0, baw1, wcat, bow0);
    // a0 = relu(xh @ aw0^T + ab0)         M=8192 N=256 K=768 -> 64x4 = 256 blocks
    staged_gemm<1, 2><<<256, 256, 0, stream>>>(xh, baw0, ab0, a0, KCAT, IDIM);
    // logits = a0 @ aw1^T + ab1           M=8192 N=256 K=256 -> 64x4 = 256 blocks
    staged_gemm<0, 2><<<256, 256, 0, stream>>>(a0, baw1, ab1, logits, IDIM, IDIM);
    attn_softmax<<<2048, 256, 0, stream>>>(logits, x, attn_o, xh);
    // fused LSTM gates                    M=8192 N=2048 K=768 -> 32x8 = 256 blocks
    gates_staged<<<256, 512, 0, stream>>>(xh, wcat, b_ih, b_hh, c,
                                          h_out, c_out, hbf);
    // hrelu = relu(h_new @ ow0^T + ob0)   M=8192 N=512 K=512 -> 64x4 = 256 blocks
    staged_gemm<1, 4><<<256, 256, 0, stream>>>(hbf, bow0, ob0, hrelu, HDIM, HDIM);
    head_gemv<<<2048, 256, 0, stream>>>(hrelu, ow1, ob1, outv);
}

// Round 11
// 106.832 us; speedup vs baseline: 1.7690x; 1.7690x over previous
//
#include <hip/hip_runtime.h>
#include <hip/hip_bf16.h>

// Problem dims
#define BROWS 8192
#define IDIM 256
#define HDIM 512
#define KCAT 768    // I + H
#define G4 2048     // 4*H

typedef __bf16 bf16_t;
typedef bf16_t bf16x8 __attribute__((ext_vector_type(8)));
typedef float f32x4 __attribute__((ext_vector_type(4)));

__device__ __forceinline__ f32x4 mfma16(bf16x8 a, bf16x8 b, f32x4 c) {
    return __builtin_amdgcn_mfma_f32_16x16x32_bf16(a, b, c, 0, 0, 0);
}

__device__ __forceinline__ ushort f2bf(float f) {
    union { float f; unsigned u; } v; v.f = f;
    unsigned u = v.u;
    unsigned r = (u + 0x7fffu + ((u >> 16) & 1u)) >> 16;  // RNE, inputs finite
    return (ushort)r;
}

__device__ __forceinline__ float bf2f(ushort u) {
    union { unsigned u; float f; } v; v.u = (unsigned)u << 16; return v.f;
}

__device__ __forceinline__ float sigmoidf_(float x) {
    return 1.f / (1.f + __expf(-x));
}
__device__ __forceinline__ float tanhf_(float x) {
    return 1.f - 2.f / (__expf(2.f * x) + 1.f);   // safe at +/-inf
}

// async global -> LDS, 16 bytes per lane (lds dest: wave-uniform base + lane*16)
typedef __attribute__((address_space(1))) const unsigned gas_u32;
typedef __attribute__((address_space(3))) unsigned las_u32;
__device__ __forceinline__ void gld_lds16(const void* g, void* l) {
    __builtin_amdgcn_global_load_lds((gas_u32*)g, (las_u32*)l, 16, 0, 0);
}

// ---------------- prep: fp32 -> bf16 packing (float4 vectorized) ----------------
__global__ void __launch_bounds__(256) prep_kernel(
        const float* __restrict__ x, const float* __restrict__ h,
        const float* __restrict__ aw0, const float* __restrict__ aw1,
        const float* __restrict__ w_ih, const float* __restrict__ w_hh,
        const float* __restrict__ ow0,
        ushort* __restrict__ xh, ushort* __restrict__ baw0,
        ushort* __restrict__ baw1, ushort* __restrict__ wcat,
        ushort* __restrict__ bow0) {
    int idx = (blockIdx.x * 256 + threadIdx.x) * 4;
    const int N_XH = BROWS * KCAT;      // 6291456
    const int N_AW0 = IDIM * KCAT;      // 196608
    const int N_AW1 = IDIM * IDIM;      // 65536
    const int N_WCAT = G4 * KCAT;       // 1572864
    const int N_OW0 = HDIM * HDIM;      // 262144
    float4 v;
    ushort* dst;
    if (idx < N_XH) {
        int b = idx / KCAT, k = idx - b * KCAT;
        v = (k < IDIM) ? *(const float4*)&x[b * IDIM + k]
                       : *(const float4*)&h[b * HDIM + (k - IDIM)];
        dst = &xh[idx];
    } else if ((idx -= N_XH) < N_AW0) {
        v = *(const float4*)&aw0[idx]; dst = &baw0[idx];
    } else if ((idx -= N_AW0) < N_AW1) {
        v = *(const float4*)&aw1[idx]; dst = &baw1[idx];
    } else if ((idx -= N_AW1) < N_WCAT) {
        int o = idx / KCAT, k = idx - o * KCAT;
        v = (k < IDIM) ? *(const float4*)&w_ih[o * IDIM + k]
                       : *(const float4*)&w_hh[o * HDIM + (k - IDIM)];
        dst = &wcat[idx];
    } else if ((idx -= N_WCAT) < N_OW0) {
        v = *(const float4*)&ow0[idx]; dst = &bow0[idx];
    } else {
        return;
    }
    ushort4 o4 = { f2bf(v.x), f2bf(v.y), f2bf(v.z), f2bf(v.w) };
    *(ushort4*)dst = o4;
}

// ---------------- staged GEMM: C = act(A @ W^T + bias) ----------------
// R8 structure (128 x NFRAG*32 tile, 4 waves, 2-buf, coalesced staging,
// both-sides chunk-XOR swizzle) with counted-vmcnt two-barrier loop:
//   barrierA -> stage(t+1) -> vmcnt(own tile t) -> barrierB -> compute(t)
// barrierA separates compute(t-1)'s LDS reads (complete before its last MFMA
// via compiler lgkmcnt) from stage(t+1)'s overwrite of slot (t-1)&1.
// vmcnt(N) retires exactly tile t's N loads; tile t+1's stay in flight.
template<int RELU_BF16, int NFRAG>
__global__ void __launch_bounds__(256) staged_gemm(
        const ushort* __restrict__ A, const ushort* __restrict__ W,
        const float* __restrict__ bias, void* __restrict__ outp,
        int Kdim, int out_ld) {
    __shared__ ushort As[2][4096];
    __shared__ ushort Ws[2][NFRAG * 1024];
    const int tid = threadIdx.x;
    const int lane = tid & 63, wave = tid >> 6;
    const int wm = wave >> 1, wn = wave & 1;
    const int r = lane & 15, g = lane >> 4;
    const int rb = blockIdx.x & 63, cb = blockIdx.x >> 6;
    const int row0 = rb * 128, col0 = cb * (NFRAG * 32);
    const int s_row = tid >> 2;
    const int s_sw = ((tid & 3) ^ ((s_row >> 1) & 3)) * 8;

    const ushort* aBase = A + (size_t)(row0 + s_row) * Kdim + s_sw;
    const ushort* wBase = W + (size_t)(col0 + s_row) * Kdim + s_sw;
    const int step64 = 64 * Kdim;
    const int rsw = (g ^ ((r >> 1) & 3)) * 8;

    f32x4 acc[4][NFRAG] = {};

    auto stage = [&](int buf, int t) {
        const int o = t * 32;
        gld_lds16(aBase + o,          &As[buf][wave * 512]);
        gld_lds16(aBase + o + step64, &As[buf][2048 + wave * 512]);
        gld_lds16(wBase + o,          &Ws[buf][wave * 512]);
        if (NFRAG == 4)
            gld_lds16(wBase + o + step64, &Ws[buf][2048 + wave * 512]);
    };
    auto compute = [&](int buf) {
        bf16x8 af[4], wf[NFRAG];
#pragma unroll
        for (int t = 0; t < 4; t++)
            af[t] = *(const bf16x8*)&As[buf][(wm * 4 + t) * 512 + r * 32 + rsw];
#pragma unroll
        for (int t = 0; t < NFRAG; t++)
            wf[t] = *(const bf16x8*)&Ws[buf][(wn * NFRAG + t) * 512 + r * 32 + rsw];
#pragma unroll
        for (int m = 0; m < 4; m++)
#pragma unroll
            for (int n = 0; n < NFRAG; n++)
                acc[m][n] = mfma16(af[m], wf[n], acc[m][n]);
    };

    stage(0, 0);
    const int NT = Kdim >> 5;
    int cur = 0;
    for (int t = 0; t < NT; t++) {
        __builtin_amdgcn_s_barrier();            // A: slot cur^1 readers done
        if (t + 1 < NT) {
            stage(cur ^ 1, t + 1);
            if (NFRAG == 4) asm volatile("s_waitcnt vmcnt(4)" ::: "memory");
            else            asm volatile("s_waitcnt vmcnt(3)" ::: "memory");
        } else {
            asm volatile("s_waitcnt vmcnt(0)" ::: "memory");
        }
        __builtin_amdgcn_s_barrier();            // B: all waves' tile t in LDS
        compute(cur);
        cur ^= 1;
    }

#pragma unroll
    for (int n = 0; n < NFRAG; n++) {
        int col = col0 + wn * (NFRAG * 16) + n * 16 + r;
        float bv = bias[col];
#pragma unroll
        for (int m = 0; m < 4; m++) {
            int rbase = row0 + wm * 64 + m * 16 + g * 4;
#pragma unroll
            for (int reg = 0; reg < 4; reg++) {
                float v = acc[m][n][reg] + bv;
                if (RELU_BF16) {
                    v = v > 0.f ? v : 0.f;
                    ((ushort*)outp)[(size_t)(rbase + reg) * out_ld + col] = f2bf(v);
                } else {
                    ((float*)outp)[(size_t)(rbase + reg) * out_ld + col] = v;
                }
            }
        }
    }
}

// ---------------- rowwise softmax + attn out + x_att into xh ----------------
__global__ void __launch_bounds__(256) attn_softmax(
        const float* __restrict__ logits, const float* __restrict__ x,
        float* __restrict__ attn_out, ushort* __restrict__ xh) {
    const int wave = threadIdx.x >> 6, lane = threadIdx.x & 63;
    const int row = blockIdx.x * 4 + wave;
    float v[4];
    float m = -1e30f;
#pragma unroll
    for (int i = 0; i < 4; i++) {
        v[i] = logits[row * IDIM + i * 64 + lane];
        m = fmaxf(m, v[i]);
    }
#pragma unroll
    for (int s = 32; s; s >>= 1) m = fmaxf(m, __shfl_xor(m, s, 64));
    float sum = 0.f;
#pragma unroll
    for (int i = 0; i < 4; i++) { v[i] = __expf(v[i] - m); sum += v[i]; }
#pragma unroll
    for (int s = 32; s; s >>= 1) sum += __shfl_xor(sum, s, 64);
    float inv = 1.f / sum;
#pragma unroll
    for (int i = 0; i < 4; i++) {
        int idx = i * 64 + lane;
        float a = v[i] * inv;
        attn_out[row * IDIM + idx] = a;
        xh[row * KCAT + idx] = f2bf(x[row * IDIM + idx] * a);
    }
}

// ---------------- fused gates GEMM + LSTM epilogue ----------------
// gates = [x_att|h] @ [w_ih|w_hh]^T : M=8192, j=512, 4 gates, K=768.
// R8 geometry: 128x128 tile (4 gates x 32 j), 4 waves, 2-buf 32KB LDS,
// grid dim3(64,16) = 1024 blocks = 4/CU. Counted-vmcnt two-barrier loop.
// Column remap puts gate on fragment index n: acc[m][0..3] = (i,f,g,o).
__global__ void __launch_bounds__(256) gates_staged(
        const ushort* __restrict__ A, const ushort* __restrict__ W,
        const float* __restrict__ b_ih, const float* __restrict__ b_hh,
        const float* __restrict__ c_in,
        float* __restrict__ h_out, float* __restrict__ c_out,
        ushort* __restrict__ h_bf) {
    __shared__ ushort As[2][4096];
    __shared__ ushort Ws[2][4096];
    const int tid = threadIdx.x;
    const int lane = tid & 63, wave = tid >> 6;
    const int wm = wave >> 1, wn = wave & 1;
    const int r = lane & 15, g = lane >> 4;
    const int row0 = blockIdx.x * 128;
    const int j0 = blockIdx.y * 32;
    const int s_row = tid >> 2;                            // 0..63
    const int s_sw = ((tid & 3) ^ ((s_row >> 1) & 3)) * 8; // swizzled chunk
    const int rsw = (g ^ ((r >> 1) & 3)) * 8;              // read-side swizzle

    auto wrow = [&](int cc) {
        return ((cc >> 4) & 3) * HDIM + j0 + (cc & 15) + ((cc >> 6) << 4);
    };
    const ushort* aBase = A + (size_t)(row0 + s_row) * KCAT + s_sw;
    const ushort* w0p = W + (size_t)wrow(s_row) * KCAT + s_sw;
    const ushort* w1p = W + (size_t)wrow(s_row + 64) * KCAT + s_sw;

    f32x4 acc[4][4] = {};

    auto stage = [&](int buf, int t) {
        const int o = t * 32;
        gld_lds16(aBase + o,             &As[buf][wave * 512]);
        gld_lds16(aBase + o + 64 * KCAT, &As[buf][2048 + wave * 512]);
        gld_lds16(w0p + o,               &Ws[buf][wave * 512]);
        gld_lds16(w1p + o,               &Ws[buf][2048 + wave * 512]);
    };
    auto compute = [&](int buf) {
        bf16x8 af[4], wf[4];
#pragma unroll
        for (int t = 0; t < 4; t++)
            af[t] = *(const bf16x8*)&As[buf][(wm * 4 + t) * 512 + r * 32 + rsw];
#pragma unroll
        for (int t = 0; t < 4; t++)
            wf[t] = *(const bf16x8*)&Ws[buf][(wn * 4 + t) * 512 + r * 32 + rsw];
#pragma unroll
        for (int m = 0; m < 4; m++)
#pragma unroll
            for (int n = 0; n < 4; n++)
                acc[m][n] = mfma16(af[m], wf[n], acc[m][n]);
    };

    stage(0, 0);
    const int NT = KCAT >> 5;   // 24
    int cur = 0;
    for (int t = 0; t < NT; t++) {
        __builtin_amdgcn_s_barrier();            // A: slot cur^1 readers done
        if (t + 1 < NT) {
            stage(cur ^ 1, t + 1);
            asm volatile("s_waitcnt vmcnt(4)" ::: "memory");  // tile t landed
        } else {
            asm volatile("s_waitcnt vmcnt(0)" ::: "memory");
        }
        __builtin_amdgcn_s_barrier();            // B: all waves' tile t in LDS
        compute(cur);
        cur ^= 1;
    }

    // LSTM epilogue: lane-local. j fixed per lane; gate = fragment index n.
    const int j = j0 + wn * 16 + r;
    float bb[4];
#pragma unroll
    for (int n = 0; n < 4; n++) bb[n] = b_ih[n * HDIM + j] + b_hh[n * HDIM + j];
#pragma unroll
    for (int m = 0; m < 4; m++) {
        int rbase = row0 + wm * 64 + m * 16 + g * 4;
#pragma unroll
        for (int reg = 0; reg < 4; reg++) {
            int row = rbase + reg;
            float ig = sigmoidf_(acc[m][0][reg] + bb[0]);
            float fg = sigmoidf_(acc[m][1][reg] + bb[1]);
            float gg = tanhf_(acc[m][2][reg] + bb[2]);
            float og = sigmoidf_(acc[m][3][reg] + bb[3]);
            float cn = fg * c_in[(size_t)row * HDIM + j] + ig * gg;
            float hn = og * tanhf_(cn);
            c_out[(size_t)row * HDIM + j] = cn;
            h_out[(size_t)row * HDIM + j] = hn;
            h_bf[(size_t)row * HDIM + j] = f2bf(hn);
        }
    }
}

// ---------------- head GEMV: out = sigmoid(hrelu . ow1 + ob1) ----------------
__global__ void __launch_bounds__(256) head_gemv(
        const ushort* __restrict__ Hrelu, const float* __restrict__ ow1,
        const float* __restrict__ ob1, float* __restrict__ outp) {
    const int wave = threadIdx.x >> 6, lane = threadIdx.x & 63;
    const int row = blockIdx.x * 4 + wave;
    typedef ushort u16x8 __attribute__((ext_vector_type(8)));
    u16x8 hv = *(const u16x8*)&Hrelu[(size_t)row * HDIM + lane * 8];
    float4 w0 = *(const float4*)&ow1[lane * 8];
    float4 w1 = *(const float4*)&ow1[lane * 8 + 4];
    float s = bf2f(hv[0]) * w0.x + bf2f(hv[1]) * w0.y + bf2f(hv[2]) * w0.z +
              bf2f(hv[3]) * w0.w + bf2f(hv[4]) * w1.x + bf2f(hv[5]) * w1.y +
              bf2f(hv[6]) * w1.z + bf2f(hv[7]) * w1.w;
#pragma unroll
    for (int sh = 32; sh; sh >>= 1) s += __shfl_xor(s, sh, 64);
    if (lane == 0) outp[row] = 1.f / (1.f + __expf(-(s + ob1[0])));
}

extern "C" void kernel_launch(void* const* d_in, const int* in_sizes, int n_in,
                              void* d_out, int out_size, void* d_ws, size_t ws_size,
                              hipStream_t stream) {
    const float* x    = (const float*)d_in[0];
    const float* h    = (const float*)d_in[1];
    const float* c    = (const float*)d_in[2];
    const float* aw0  = (const float*)d_in[3];
    const float* ab0  = (const float*)d_in[4];
    const float* aw1  = (const float*)d_in[5];
    const float* ab1  = (const float*)d_in[6];
    const float* w_ih = (const float*)d_in[7];
    const float* b_ih = (const float*)d_in[8];
    const float* w_hh = (const float*)d_in[9];
    const float* b_hh = (const float*)d_in[10];
    const float* ow0  = (const float*)d_in[11];
    const float* ob0  = (const float*)d_in[12];
    const float* ow1  = (const float*)d_in[13];
    const float* ob1  = (const float*)d_in[14];

    char* ws = (char*)d_ws;
    ushort* xh     = (ushort*)(ws + 0);           // 8192*768*2  = 12582912
    ushort* a0     = (ushort*)(ws + 12582912);    // 8192*256*2  = 4194304
    float*  logits = (float*) (ws + 16777216);    // 8192*256*4  = 8388608
    ushort* hrelu  = (ushort*)(ws + 16777216);    // aliases logits (dead after softmax)
    ushort* hbf    = (ushort*)(ws + 25165824);    // 8192*512*2  = 8388608
    ushort* baw0   = (ushort*)(ws + 33554432);    // 256*768*2   = 393216
    ushort* baw1   = (ushort*)(ws + 33947648);    // 256*256*2   = 131072
    ushort* wcat   = (ushort*)(ws + 34078720);    // 2048*768*2  = 3145728
    ushort* bow0   = (ushort*)(ws + 37224448);    // 512*512*2   = 524288

    float* outv    = (float*)d_out;               // [8192]
    float* h_out   = outv + 8192;                 // [8192,512]
    float* c_out   = outv + 4202496;              // [8192,512]
    float* attn_o  = outv + 8396800;              // [8192,256]

    prep_kernel<<<8192, 256, 0, stream>>>(x, h, aw0, aw1, w_ih, w_hh, ow0,
                                          xh, baw0, baw1, wcat, bow0);
    // a0 = relu(xh @ aw0^T + ab0)         M=8192 N=256 K=768 -> 64x4 = 256 blocks
    staged_gemm<1, 2><<<256, 256, 0, stream>>>(xh, baw0, ab0, a0, KCAT, IDIM);
    // logits = a0 @ aw1^T + ab1           M=8192 N=256 K=256 -> 64x4 = 256 blocks
    staged_gemm<0, 2><<<256, 256, 0, stream>>>(a0, baw1, ab1, logits, IDIM, IDIM);
    attn_softmax<<<2048, 256, 0, stream>>>(logits, x, attn_o, xh);
    // fused LSTM gates                    M=8192 N=2048 K=768 -> 64x16 = 1024 blocks
    gates_staged<<<dim3(64, 16), 256, 0, stream>>>(xh, wcat, b_ih, b_hh, c,
                                                   h_out, c_out, hbf);
    // hrelu = relu(h_new @ ow0^T + ob0)   M=8192 N=512 K=512 -> 64x4 = 256 blocks
    staged_gemm<1, 4><<<256, 256, 0, stream>>>(hbf, bow0, ob0, hrelu, HDIM, HDIM);
    head_gemv<<<2048, 256, 0, stream>>>(hrelu, ow1, ob1, outv);
}

// Round 12
// 100.369 us; speedup vs baseline: 1.8829x; 1.0644x over previous
//
#include <hip/hip_runtime.h>
#include <hip/hip_bf16.h>

// Problem dims
#define BROWS 8192
#define IDIM 256
#define HDIM 512
#define KCAT 768    // I + H
#define G4 2048     // 4*H

typedef __bf16 bf16_t;
typedef bf16_t bf16x8 __attribute__((ext_vector_type(8)));
typedef float f32x4 __attribute__((ext_vector_type(4)));

__device__ __forceinline__ f32x4 mfma16(bf16x8 a, bf16x8 b, f32x4 c) {
    return __builtin_amdgcn_mfma_f32_16x16x32_bf16(a, b, c, 0, 0, 0);
}

__device__ __forceinline__ ushort f2bf(float f) {
    union { float f; unsigned u; } v; v.f = f;
    unsigned u = v.u;
    unsigned r = (u + 0x7fffu + ((u >> 16) & 1u)) >> 16;  // RNE, inputs finite
    return (ushort)r;
}

__device__ __forceinline__ float bf2f(ushort u) {
    union { unsigned u; float f; } v; v.u = (unsigned)u << 16; return v.f;
}

__device__ __forceinline__ float sigmoidf_(float x) {
    return 1.f / (1.f + __expf(-x));
}
__device__ __forceinline__ float tanhf_(float x) {
    return 1.f - 2.f / (__expf(2.f * x) + 1.f);   // safe at +/-inf
}

// async global -> LDS, 16 bytes per lane (lds dest: wave-uniform base + lane*16)
typedef __attribute__((address_space(1))) const unsigned gas_u32;
typedef __attribute__((address_space(3))) unsigned las_u32;
__device__ __forceinline__ void gld_lds16(const void* g, void* l) {
    __builtin_amdgcn_global_load_lds((gas_u32*)g, (las_u32*)l, 16, 0, 0);
}

// ---------------- prep: fp32 -> bf16 packing (float4 vectorized) ----------------
__global__ void __launch_bounds__(256) prep_kernel(
        const float* __restrict__ x, const float* __restrict__ h,
        const float* __restrict__ aw0, const float* __restrict__ aw1,
        const float* __restrict__ w_ih, const float* __restrict__ w_hh,
        const float* __restrict__ ow0,
        ushort* __restrict__ xh, ushort* __restrict__ baw0,
        ushort* __restrict__ baw1, ushort* __restrict__ wcat,
        ushort* __restrict__ bow0) {
    int idx = (blockIdx.x * 256 + threadIdx.x) * 4;
    const int N_XH = BROWS * KCAT;      // 6291456
    const int N_AW0 = IDIM * KCAT;      // 196608
    const int N_AW1 = IDIM * IDIM;      // 65536
    const int N_WCAT = G4 * KCAT;       // 1572864
    const int N_OW0 = HDIM * HDIM;      // 262144
    float4 v;
    ushort* dst;
    if (idx < N_XH) {
        int b = idx / KCAT, k = idx - b * KCAT;
        v = (k < IDIM) ? *(const float4*)&x[b * IDIM + k]
                       : *(const float4*)&h[b * HDIM + (k - IDIM)];
        dst = &xh[idx];
    } else if ((idx -= N_XH) < N_AW0) {
        v = *(const float4*)&aw0[idx]; dst = &baw0[idx];
    } else if ((idx -= N_AW0) < N_AW1) {
        v = *(const float4*)&aw1[idx]; dst = &baw1[idx];
    } else if ((idx -= N_AW1) < N_WCAT) {
        int o = idx / KCAT, k = idx - o * KCAT;
        v = (k < IDIM) ? *(const float4*)&w_ih[o * IDIM + k]
                       : *(const float4*)&w_hh[o * HDIM + (k - IDIM)];
        dst = &wcat[idx];
    } else if ((idx -= N_WCAT) < N_OW0) {
        v = *(const float4*)&ow0[idx]; dst = &bow0[idx];
    } else {
        return;
    }
    ushort4 o4 = { f2bf(v.x), f2bf(v.y), f2bf(v.z), f2bf(v.w) };
    *(ushort4*)dst = o4;
}

// ---------------- staged GEMM (small GEMMs; R8/R11-proven, unchanged) ----------------
template<int RELU_BF16, int NFRAG>
__global__ void __launch_bounds__(256) staged_gemm(
        const ushort* __restrict__ A, const ushort* __restrict__ W,
        const float* __restrict__ bias, void* __restrict__ outp,
        int Kdim, int out_ld) {
    __shared__ ushort As[2][4096];
    __shared__ ushort Ws[2][NFRAG * 1024];
    const int tid = threadIdx.x;
    const int lane = tid & 63, wave = tid >> 6;
    const int wm = wave >> 1, wn = wave & 1;
    const int r = lane & 15, g = lane >> 4;
    const int rb = blockIdx.x & 63, cb = blockIdx.x >> 6;
    const int row0 = rb * 128, col0 = cb * (NFRAG * 32);
    const int s_row = tid >> 2;
    const int s_sw = ((tid & 3) ^ ((s_row >> 1) & 3)) * 8;

    const ushort* aBase = A + (size_t)(row0 + s_row) * Kdim + s_sw;
    const ushort* wBase = W + (size_t)(col0 + s_row) * Kdim + s_sw;
    const int step64 = 64 * Kdim;
    const int rsw = (g ^ ((r >> 1) & 3)) * 8;

    f32x4 acc[4][NFRAG] = {};

    auto stage = [&](int buf, int t) {
        const int o = t * 32;
        gld_lds16(aBase + o,          &As[buf][wave * 512]);
        gld_lds16(aBase + o + step64, &As[buf][2048 + wave * 512]);
        gld_lds16(wBase + o,          &Ws[buf][wave * 512]);
        if (NFRAG == 4)
            gld_lds16(wBase + o + step64, &Ws[buf][2048 + wave * 512]);
    };
    auto compute = [&](int buf) {
        bf16x8 af[4], wf[NFRAG];
#pragma unroll
        for (int t = 0; t < 4; t++)
            af[t] = *(const bf16x8*)&As[buf][(wm * 4 + t) * 512 + r * 32 + rsw];
#pragma unroll
        for (int t = 0; t < NFRAG; t++)
            wf[t] = *(const bf16x8*)&Ws[buf][(wn * NFRAG + t) * 512 + r * 32 + rsw];
#pragma unroll
        for (int m = 0; m < 4; m++)
#pragma unroll
            for (int n = 0; n < NFRAG; n++)
                acc[m][n] = mfma16(af[m], wf[n], acc[m][n]);
    };

    stage(0, 0);
    const int NT = Kdim >> 5;
    int cur = 0;
    for (int t = 0; t < NT; t++) {
        __builtin_amdgcn_s_barrier();            // A: slot cur^1 readers done
        if (t + 1 < NT) {
            stage(cur ^ 1, t + 1);
            if (NFRAG == 4) asm volatile("s_waitcnt vmcnt(4)" ::: "memory");
            else            asm volatile("s_waitcnt vmcnt(3)" ::: "memory");
        } else {
            asm volatile("s_waitcnt vmcnt(0)" ::: "memory");
        }
        __builtin_amdgcn_s_barrier();            // B: all waves' tile t in LDS
        compute(cur);
        cur ^= 1;
    }

#pragma unroll
    for (int n = 0; n < NFRAG; n++) {
        int col = col0 + wn * (NFRAG * 16) + n * 16 + r;
        float bv = bias[col];
#pragma unroll
        for (int m = 0; m < 4; m++) {
            int rbase = row0 + wm * 64 + m * 16 + g * 4;
#pragma unroll
            for (int reg = 0; reg < 4; reg++) {
                float v = acc[m][n][reg] + bv;
                if (RELU_BF16) {
                    v = v > 0.f ? v : 0.f;
                    ((ushort*)outp)[(size_t)(rbase + reg) * out_ld + col] = f2bf(v);
                } else {
                    ((float*)outp)[(size_t)(rbase + reg) * out_ld + col] = v;
                }
            }
        }
    }
}

// ---------------- rowwise softmax + attn out + x_att into xh ----------------
__global__ void __launch_bounds__(256) attn_softmax(
        const float* __restrict__ logits, const float* __restrict__ x,
        float* __restrict__ attn_out, ushort* __restrict__ xh) {
    const int wave = threadIdx.x >> 6, lane = threadIdx.x & 63;
    const int row = blockIdx.x * 4 + wave;
    float v[4];
    float m = -1e30f;
#pragma unroll
    for (int i = 0; i < 4; i++) {
        v[i] = logits[row * IDIM + i * 64 + lane];
        m = fmaxf(m, v[i]);
    }
#pragma unroll
    for (int s = 32; s; s >>= 1) m = fmaxf(m, __shfl_xor(m, s, 64));
    float sum = 0.f;
#pragma unroll
    for (int i = 0; i < 4; i++) { v[i] = __expf(v[i] - m); sum += v[i]; }
#pragma unroll
    for (int s = 32; s; s >>= 1) sum += __shfl_xor(sum, s, 64);
    float inv = 1.f / sum;
#pragma unroll
    for (int i = 0; i < 4; i++) {
        int idx = i * 64 + lane;
        float a = v[i] * inv;
        attn_out[row * IDIM + idx] = a;
        xh[row * KCAT + idx] = f2bf(x[row * IDIM + idx] * a);
    }
}

// ---------------- fused gates GEMM + LSTM epilogue (8-wave TLP variant) ----------------
// gates = [x_att|h] @ [w_ih|w_hh]^T : M=8192, j=512, 4 gates, K=768.
// SAME tile/grid/bytes as R11 (128x128, BK=32, dim3(64,16)=1024 blocks, 2-buf
// 32KB LDS, both-sides chunk-XOR swizzle, counted-vmcnt two-barrier loop).
// ONLY change: 8 waves/block (512 thr), wave tile 32x64 -> acc[2][4]=32 VGPR,
// ~70 total -> 3-4 blocks/CU = 24-32 waves/CU (vs 16). Pure TLP experiment:
// per-wave staging rate ~0.48 B/cy is the measured invariant; more resident
// waves = proportionally higher per-CU staging rate.
// Wave (wm=wave>>1 in 0..3, wn=wave&1): rows wm*32+m*16, cols wn*64+n*16+r
// -> gate = n, j = j0 + wn*16 + r: LSTM epilogue stays lane-local.
// Staging: wave w stages A-subtile w (rows 16w..16w+15) + W-subtile w
// (LDS cols 16w..16w+15), 2 gld_lds each; vmcnt(2) retires own tile t.
__global__ void __launch_bounds__(512, 6) gates_staged(
        const ushort* __restrict__ A, const ushort* __restrict__ W,
        const float* __restrict__ b_ih, const float* __restrict__ b_hh,
        const float* __restrict__ c_in,
        float* __restrict__ h_out, float* __restrict__ c_out,
        ushort* __restrict__ h_bf) {
    __shared__ ushort As[2][4096];
    __shared__ ushort Ws[2][4096];
    const int tid = threadIdx.x;
    const int lane = tid & 63, wave = tid >> 6;   // 8 waves
    const int wm = wave >> 1, wn = wave & 1;      // 4M x 2N
    const int r = lane & 15, g = lane >> 4;
    const int row0 = blockIdx.x * 128;
    const int j0 = blockIdx.y * 32;
    const int rl = lane >> 2, chq = lane & 3;     // staging: row-in-subtile, chunk
    const int s_sw = (chq ^ ((rl >> 1) & 3)) * 8; // pre-swizzled source chunk
    const int rsw = (g ^ ((r >> 1) & 3)) * 8;     // read-side swizzle

    auto wrow = [&](int cc) {
        return ((cc >> 4) & 3) * HDIM + j0 + (cc & 15) + ((cc >> 6) << 4);
    };
    const ushort* aP = A + (size_t)(row0 + wave * 16 + rl) * KCAT + s_sw;
    const ushort* wP = W + (size_t)wrow(wave * 16 + rl) * KCAT + s_sw;

    f32x4 acc[2][4] = {};

    auto stage = [&](int buf, int t) {
        const int o = t * 32;
        gld_lds16(aP + o, &As[buf][wave * 512]);
        gld_lds16(wP + o, &Ws[buf][wave * 512]);
    };
    auto compute = [&](int buf) {
        bf16x8 af[2], wf[4];
#pragma unroll
        for (int m = 0; m < 2; m++)
            af[m] = *(const bf16x8*)&As[buf][(wm * 2 + m) * 512 + r * 32 + rsw];
#pragma unroll
        for (int n = 0; n < 4; n++)
            wf[n] = *(const bf16x8*)&Ws[buf][(wn * 4 + n) * 512 + r * 32 + rsw];
#pragma unroll
        for (int m = 0; m < 2; m++)
#pragma unroll
            for (int n = 0; n < 4; n++)
                acc[m][n] = mfma16(af[m], wf[n], acc[m][n]);
    };

    stage(0, 0);
    const int NT = KCAT >> 5;   // 24
    int cur = 0;
    for (int t = 0; t < NT; t++) {
        __builtin_amdgcn_s_barrier();            // A: slot cur^1 readers done
        if (t + 1 < NT) {
            stage(cur ^ 1, t + 1);
            asm volatile("s_waitcnt vmcnt(2)" ::: "memory");  // own tile t landed
        } else {
            asm volatile("s_waitcnt vmcnt(0)" ::: "memory");
        }
        __builtin_amdgcn_s_barrier();            // B: all waves' tile t in LDS
        compute(cur);
        cur ^= 1;
    }

    // LSTM epilogue: lane-local. j fixed per lane; gate = fragment index n.
    const int j = j0 + wn * 16 + r;
    float bb[4];
#pragma unroll
    for (int n = 0; n < 4; n++) bb[n] = b_ih[n * HDIM + j] + b_hh[n * HDIM + j];
#pragma unroll
    for (int m = 0; m < 2; m++) {
        int rbase = row0 + wm * 32 + m * 16 + g * 4;
#pragma unroll
        for (int reg = 0; reg < 4; reg++) {
            int row = rbase + reg;
            float ig = sigmoidf_(acc[m][0][reg] + bb[0]);
            float fg = sigmoidf_(acc[m][1][reg] + bb[1]);
            float gg = tanhf_(acc[m][2][reg] + bb[2]);
            float og = sigmoidf_(acc[m][3][reg] + bb[3]);
            float cn = fg * c_in[(size_t)row * HDIM + j] + ig * gg;
            float hn = og * tanhf_(cn);
            c_out[(size_t)row * HDIM + j] = cn;
            h_out[(size_t)row * HDIM + j] = hn;
            h_bf[(size_t)row * HDIM + j] = f2bf(hn);
        }
    }
}

// ---------------- head GEMV: out = sigmoid(hrelu . ow1 + ob1) ----------------
__global__ void __launch_bounds__(256) head_gemv(
        const ushort* __restrict__ Hrelu, const float* __restrict__ ow1,
        const float* __restrict__ ob1, float* __restrict__ outp) {
    const int wave = threadIdx.x >> 6, lane = threadIdx.x & 63;
    const int row = blockIdx.x * 4 + wave;
    typedef ushort u16x8 __attribute__((ext_vector_type(8)));
    u16x8 hv = *(const u16x8*)&Hrelu[(size_t)row * HDIM + lane * 8];
    float4 w0 = *(const float4*)&ow1[lane * 8];
    float4 w1 = *(const float4*)&ow1[lane * 8 + 4];
    float s = bf2f(hv[0]) * w0.x + bf2f(hv[1]) * w0.y + bf2f(hv[2]) * w0.z +
              bf2f(hv[3]) * w0.w + bf2f(hv[4]) * w1.x + bf2f(hv[5]) * w1.y +
              bf2f(hv[6]) * w1.z + bf2f(hv[7]) * w1.w;
#pragma unroll
    for (int sh = 32; sh; sh >>= 1) s += __shfl_xor(s, sh, 64);
    if (lane == 0) outp[row] = 1.f / (1.f + __expf(-(s + ob1[0])));
}

extern "C" void kernel_launch(void* const* d_in, const int* in_sizes, int n_in,
                              void* d_out, int out_size, void* d_ws, size_t ws_size,
                              hipStream_t stream) {
    const float* x    = (const float*)d_in[0];
    const float* h    = (const float*)d_in[1];
    const float* c    = (const float*)d_in[2];
    const float* aw0  = (const float*)d_in[3];
    const float* ab0  = (const float*)d_in[4];
    const float* aw1  = (const float*)d_in[5];
    const float* ab1  = (const float*)d_in[6];
    const float* w_ih = (const float*)d_in[7];
    const float* b_ih = (const float*)d_in[8];
    const float* w_hh = (const float*)d_in[9];
    const float* b_hh = (const float*)d_in[10];
    const float* ow0  = (const float*)d_in[11];
    const float* ob0  = (const float*)d_in[12];
    const float* ow1  = (const float*)d_in[13];
    const float* ob1  = (const float*)d_in[14];

    char* ws = (char*)d_ws;
    ushort* xh     = (ushort*)(ws + 0);           // 8192*768*2  = 12582912
    ushort* a0     = (ushort*)(ws + 12582912);    // 8192*256*2  = 4194304
    float*  logits = (float*) (ws + 16777216);    // 8192*256*4  = 8388608
    ushort* hrelu  = (ushort*)(ws + 16777216);    // aliases logits (dead after softmax)
    ushort* hbf    = (ushort*)(ws + 25165824);    // 8192*512*2  = 8388608
    ushort* baw0   = (ushort*)(ws + 33554432);    // 256*768*2   = 393216
    ushort* baw1   = (ushort*)(ws + 33947648);    // 256*256*2   = 131072
    ushort* wcat   = (ushort*)(ws + 34078720);    // 2048*768*2  = 3145728
    ushort* bow0   = (ushort*)(ws + 37224448);    // 512*512*2   = 524288

    float* outv    = (float*)d_out;               // [8192]
    float* h_out   = outv + 8192;                 // [8192,512]
    float* c_out   = outv + 4202496;              // [8192,512]
    float* attn_o  = outv + 8396800;              // [8192,256]

    prep_kernel<<<8192, 256, 0, stream>>>(x, h, aw0, aw1, w_ih, w_hh, ow0,
                                          xh, baw0, baw1, wcat, bow0);
    // a0 = relu(xh @ aw0^T + ab0)         M=8192 N=256 K=768 -> 64x4 = 256 blocks
    staged_gemm<1, 2><<<256, 256, 0, stream>>>(xh, baw0, ab0, a0, KCAT, IDIM);
    // logits = a0 @ aw1^T + ab1           M=8192 N=256 K=256 -> 64x4 = 256 blocks
    staged_gemm<0, 2><<<256, 256, 0, stream>>>(a0, baw1, ab1, logits, IDIM, IDIM);
    attn_softmax<<<2048, 256, 0, stream>>>(logits, x, attn_o, xh);
    // fused LSTM gates                    M=8192 N=2048 K=768 -> 64x16 = 1024 blocks (8-wave)
    gates_staged<<<dim3(64, 16), 512, 0, stream>>>(xh, wcat, b_ih, b_hh, c,
                                                   h_out, c_out, hbf);
    // hrelu = relu(h_new @ ow0^T + ob0)   M=8192 N=512 K=512 -> 64x4 = 256 blocks
    staged_gemm<1, 4><<<256, 256, 0, stream>>>(hbf, bow0, ob0, hrelu, HDIM, HDIM);
    head_gemv<<<2048, 256, 0, stream>>>(hrelu, ow1, ob1, outv);
}

// Round 13
// 91.722 us; speedup vs baseline: 2.0605x; 1.0943x over previous
//
#include <hip/hip_runtime.h>
#include <hip/hip_bf16.h>

// Problem dims
#define BROWS 8192
#define IDIM 256
#define HDIM 512
#define KCAT 768    // I + H
#define G4 2048     // 4*H

typedef __bf16 bf16_t;
typedef bf16_t bf16x8 __attribute__((ext_vector_type(8)));
typedef float f32x4 __attribute__((ext_vector_type(4)));

__device__ __forceinline__ f32x4 mfma16(bf16x8 a, bf16x8 b, f32x4 c) {
    return __builtin_amdgcn_mfma_f32_16x16x32_bf16(a, b, c, 0, 0, 0);
}

__device__ __forceinline__ ushort f2bf(float f) {
    union { float f; unsigned u; } v; v.f = f;
    unsigned u = v.u;
    unsigned r = (u + 0x7fffu + ((u >> 16) & 1u)) >> 16;  // RNE, inputs finite
    return (ushort)r;
}

__device__ __forceinline__ float bf2f(ushort u) {
    union { unsigned u; float f; } v; v.u = (unsigned)u << 16; return v.f;
}

__device__ __forceinline__ float sigmoidf_(float x) {
    return 1.f / (1.f + __expf(-x));
}
__device__ __forceinline__ float tanhf_(float x) {
    return 1.f - 2.f / (__expf(2.f * x) + 1.f);   // safe at +/-inf
}

// async global -> LDS, 16 bytes per lane (lds dest: wave-uniform base + lane*16)
typedef __attribute__((address_space(1))) const unsigned gas_u32;
typedef __attribute__((address_space(3))) unsigned las_u32;
__device__ __forceinline__ void gld_lds16(const void* g, void* l) {
    __builtin_amdgcn_global_load_lds((gas_u32*)g, (las_u32*)l, 16, 0, 0);
}

// ---------------- prep: fp32 -> bf16 packing (float4 vectorized) ----------------
__global__ void __launch_bounds__(256) prep_kernel(
        const float* __restrict__ x, const float* __restrict__ h,
        const float* __restrict__ aw0, const float* __restrict__ aw1,
        const float* __restrict__ w_ih, const float* __restrict__ w_hh,
        const float* __restrict__ ow0,
        ushort* __restrict__ xh, ushort* __restrict__ baw0,
        ushort* __restrict__ baw1, ushort* __restrict__ wcat,
        ushort* __restrict__ bow0) {
    int idx = (blockIdx.x * 256 + threadIdx.x) * 4;
    const int N_XH = BROWS * KCAT;      // 6291456
    const int N_AW0 = IDIM * KCAT;      // 196608
    const int N_AW1 = IDIM * IDIM;      // 65536
    const int N_WCAT = G4 * KCAT;       // 1572864
    const int N_OW0 = HDIM * HDIM;      // 262144
    float4 v;
    ushort* dst;
    if (idx < N_XH) {
        int b = idx / KCAT, k = idx - b * KCAT;
        v = (k < IDIM) ? *(const float4*)&x[b * IDIM + k]
                       : *(const float4*)&h[b * HDIM + (k - IDIM)];
        dst = &xh[idx];
    } else if ((idx -= N_XH) < N_AW0) {
        v = *(const float4*)&aw0[idx]; dst = &baw0[idx];
    } else if ((idx -= N_AW0) < N_AW1) {
        v = *(const float4*)&aw1[idx]; dst = &baw1[idx];
    } else if ((idx -= N_AW1) < N_WCAT) {
        int o = idx / KCAT, k = idx - o * KCAT;
        v = (k < IDIM) ? *(const float4*)&w_ih[o * IDIM + k]
                       : *(const float4*)&w_hh[o * HDIM + (k - IDIM)];
        dst = &wcat[idx];
    } else if ((idx -= N_WCAT) < N_OW0) {
        v = *(const float4*)&ow0[idx]; dst = &bow0[idx];
    } else {
        return;
    }
    ushort4 o4 = { f2bf(v.x), f2bf(v.y), f2bf(v.z), f2bf(v.w) };
    *(ushort4*)dst = o4;
}

// ---------------- staged GEMM (small GEMMs; R8/R11-proven, unchanged) ----------------
template<int RELU_BF16, int NFRAG>
__global__ void __launch_bounds__(256) staged_gemm(
        const ushort* __restrict__ A, const ushort* __restrict__ W,
        const float* __restrict__ bias, void* __restrict__ outp,
        int Kdim, int out_ld) {
    __shared__ ushort As[2][4096];
    __shared__ ushort Ws[2][NFRAG * 1024];
    const int tid = threadIdx.x;
    const int lane = tid & 63, wave = tid >> 6;
    const int wm = wave >> 1, wn = wave & 1;
    const int r = lane & 15, g = lane >> 4;
    const int rb = blockIdx.x & 63, cb = blockIdx.x >> 6;
    const int row0 = rb * 128, col0 = cb * (NFRAG * 32);
    const int s_row = tid >> 2;
    const int s_sw = ((tid & 3) ^ ((s_row >> 1) & 3)) * 8;

    const ushort* aBase = A + (size_t)(row0 + s_row) * Kdim + s_sw;
    const ushort* wBase = W + (size_t)(col0 + s_row) * Kdim + s_sw;
    const int step64 = 64 * Kdim;
    const int rsw = (g ^ ((r >> 1) & 3)) * 8;

    f32x4 acc[4][NFRAG] = {};

    auto stage = [&](int buf, int t) {
        const int o = t * 32;
        gld_lds16(aBase + o,          &As[buf][wave * 512]);
        gld_lds16(aBase + o + step64, &As[buf][2048 + wave * 512]);
        gld_lds16(wBase + o,          &Ws[buf][wave * 512]);
        if (NFRAG == 4)
            gld_lds16(wBase + o + step64, &Ws[buf][2048 + wave * 512]);
    };
    auto compute = [&](int buf) {
        bf16x8 af[4], wf[NFRAG];
#pragma unroll
        for (int t = 0; t < 4; t++)
            af[t] = *(const bf16x8*)&As[buf][(wm * 4 + t) * 512 + r * 32 + rsw];
#pragma unroll
        for (int t = 0; t < NFRAG; t++)
            wf[t] = *(const bf16x8*)&Ws[buf][(wn * NFRAG + t) * 512 + r * 32 + rsw];
#pragma unroll
        for (int m = 0; m < 4; m++)
#pragma unroll
            for (int n = 0; n < NFRAG; n++)
                acc[m][n] = mfma16(af[m], wf[n], acc[m][n]);
    };

    stage(0, 0);
    const int NT = Kdim >> 5;
    int cur = 0;
    for (int t = 0; t < NT; t++) {
        __builtin_amdgcn_s_barrier();            // A: slot cur^1 readers done
        if (t + 1 < NT) {
            stage(cur ^ 1, t + 1);
            if (NFRAG == 4) asm volatile("s_waitcnt vmcnt(4)" ::: "memory");
            else            asm volatile("s_waitcnt vmcnt(3)" ::: "memory");
        } else {
            asm volatile("s_waitcnt vmcnt(0)" ::: "memory");
        }
        __builtin_amdgcn_s_barrier();            // B: all waves' tile t in LDS
        compute(cur);
        cur ^= 1;
    }

#pragma unroll
    for (int n = 0; n < NFRAG; n++) {
        int col = col0 + wn * (NFRAG * 16) + n * 16 + r;
        float bv = bias[col];
#pragma unroll
        for (int m = 0; m < 4; m++) {
            int rbase = row0 + wm * 64 + m * 16 + g * 4;
#pragma unroll
            for (int reg = 0; reg < 4; reg++) {
                float v = acc[m][n][reg] + bv;
                if (RELU_BF16) {
                    v = v > 0.f ? v : 0.f;
                    ((ushort*)outp)[(size_t)(rbase + reg) * out_ld + col] = f2bf(v);
                } else {
                    ((float*)outp)[(size_t)(rbase + reg) * out_ld + col] = v;
                }
            }
        }
    }
}

// ---------------- rowwise softmax + attn out + x_att into xh ----------------
__global__ void __launch_bounds__(256) attn_softmax(
        const float* __restrict__ logits, const float* __restrict__ x,
        float* __restrict__ attn_out, ushort* __restrict__ xh) {
    const int wave = threadIdx.x >> 6, lane = threadIdx.x & 63;
    const int row = blockIdx.x * 4 + wave;
    float v[4];
    float m = -1e30f;
#pragma unroll
    for (int i = 0; i < 4; i++) {
        v[i] = logits[row * IDIM + i * 64 + lane];
        m = fmaxf(m, v[i]);
    }
#pragma unroll
    for (int s = 32; s; s >>= 1) m = fmaxf(m, __shfl_xor(m, s, 64));
    float sum = 0.f;
#pragma unroll
    for (int i = 0; i < 4; i++) { v[i] = __expf(v[i] - m); sum += v[i]; }
#pragma unroll
    for (int s = 32; s; s >>= 1) sum += __shfl_xor(sum, s, 64);
    float inv = 1.f / sum;
#pragma unroll
    for (int i = 0; i < 4; i++) {
        int idx = i * 64 + lane;
        float a = v[i] * inv;
        attn_out[row * IDIM + idx] = a;
        xh[row * KCAT + idx] = f2bf(x[row * IDIM + idx] * a);
    }
}

// ---------------- fused gates GEMM + LSTM epilogue (256x256, 16-wave) ----------------
// gates = [x_att|h] @ [w_ih|w_hh]^T : M=8192, j=512, 4 gates, K=768.
// BM=BN=256 halves staged bytes vs 128^2: A x8 + W x32 = 201MB (vs 403MB).
// 16 waves (1024 thr, 4M x 4N), wave tile 64x64 -> acc[4][4]=64 VGPR (~110
// total; __launch_bounds__(1024,4) caps at 128 -- above need, R10 lesson).
// Grid 32 rb x 8 cb = 256 = 1 block/CU, 16 waves/CU, zero tail.
// LDS 64KB: 2-buf x (A 16KB + W 16KB) per K-step (BK=32).
// Loop/swizzle identical to R11/R12: both-sides chunk-XOR; counted-vmcnt
// two-barrier (barrierA -> stage(t+1) -> vmcnt(2)=own tile t -> barrierB ->
// compute(t)). Wave stages A-subtile w + W-subtile w (1KB each).
// Column mapping (R5-verified): cc = wn*64 + n*16 + r -> gate = n,
// j = j0 + wn*16 + r -> LSTM epilogue fully lane-local.
__global__ void __launch_bounds__(1024, 4) gates_staged(
        const ushort* __restrict__ A, const ushort* __restrict__ W,
        const float* __restrict__ b_ih, const float* __restrict__ b_hh,
        const float* __restrict__ c_in,
        float* __restrict__ h_out, float* __restrict__ c_out,
        ushort* __restrict__ h_bf) {
    __shared__ ushort As[2 * 8192];   // 32KB: 2 bufs x 16 subtiles x 512
    __shared__ ushort Ws[2 * 8192];   // 32KB
    const int tid = threadIdx.x;
    const int lane = tid & 63, wave = tid >> 6;   // 16 waves
    const int wm = wave >> 2, wn = wave & 3;      // 4M x 4N
    const int r = lane & 15, g = lane >> 4;
    const int bid = blockIdx.x;                   // 256 blocks
    const int xcd = bid & 7, local = bid >> 3;
    const int rb = xcd * 4 + (local & 3);         // 0..31
    const int cb = local >> 2;                    // 0..7
    const int row0 = rb * 256;
    const int j0 = cb * 64;
    const int rl = lane >> 2, chq = lane & 3;     // staging: row-in-subtile, chunk
    const int s_sw = (chq ^ ((rl >> 1) & 3)) * 8; // pre-swizzled source chunk
    const int rsw = (g ^ ((r >> 1) & 3)) * 8;     // read-side swizzle

    // W row for LDS col cc: gate=(cc>>4)&3, j = j0 + (cc&15) + ((cc>>6)<<4)
    auto wrow = [&](int cc) {
        return ((cc >> 4) & 3) * HDIM + j0 + (cc & 15) + ((cc >> 6) << 4);
    };
    const ushort* aP = A + (size_t)(row0 + wave * 16 + rl) * KCAT + s_sw;
    const ushort* wP = W + (size_t)wrow(wave * 16 + rl) * KCAT + s_sw;

    f32x4 acc[4][4] = {};

    auto stage = [&](int buf, int t) {
        const int o = t * 32;
        gld_lds16(aP + o, &As[buf * 8192 + wave * 512]);
        gld_lds16(wP + o, &Ws[buf * 8192 + wave * 512]);
    };
    auto compute = [&](int buf) {
        bf16x8 af[4], wf[4];
#pragma unroll
        for (int m = 0; m < 4; m++)
            af[m] = *(const bf16x8*)&As[buf * 8192 + (wm * 4 + m) * 512 + r * 32 + rsw];
#pragma unroll
        for (int n = 0; n < 4; n++)
            wf[n] = *(const bf16x8*)&Ws[buf * 8192 + (wn * 4 + n) * 512 + r * 32 + rsw];
#pragma unroll
        for (int m = 0; m < 4; m++)
#pragma unroll
            for (int n = 0; n < 4; n++)
                acc[m][n] = mfma16(af[m], wf[n], acc[m][n]);
    };

    stage(0, 0);
    const int NT = KCAT >> 5;   // 24
    int cur = 0;
    for (int t = 0; t < NT; t++) {
        __builtin_amdgcn_s_barrier();            // A: slot cur^1 readers done
        if (t + 1 < NT) {
            stage(cur ^ 1, t + 1);
            asm volatile("s_waitcnt vmcnt(2)" ::: "memory");  // own tile t landed
        } else {
            asm volatile("s_waitcnt vmcnt(0)" ::: "memory");
        }
        __builtin_amdgcn_s_barrier();            // B: all waves' tile t in LDS
        compute(cur);
        cur ^= 1;
    }

    // LSTM epilogue: lane-local. j fixed per lane; gate = fragment index n.
    const int j = j0 + wn * 16 + r;
    float bb[4];
#pragma unroll
    for (int n = 0; n < 4; n++) bb[n] = b_ih[n * HDIM + j] + b_hh[n * HDIM + j];
#pragma unroll
    for (int m = 0; m < 4; m++) {
        int rbase = row0 + wm * 64 + m * 16 + g * 4;
#pragma unroll
        for (int reg = 0; reg < 4; reg++) {
            int row = rbase + reg;
            float ig = sigmoidf_(acc[m][0][reg] + bb[0]);
            float fg = sigmoidf_(acc[m][1][reg] + bb[1]);
            float gg = tanhf_(acc[m][2][reg] + bb[2]);
            float og = sigmoidf_(acc[m][3][reg] + bb[3]);
            float cn = fg * c_in[(size_t)row * HDIM + j] + ig * gg;
            float hn = og * tanhf_(cn);
            c_out[(size_t)row * HDIM + j] = cn;
            h_out[(size_t)row * HDIM + j] = hn;
            h_bf[(size_t)row * HDIM + j] = f2bf(hn);
        }
    }
}

// ---------------- head GEMV: out = sigmoid(hrelu . ow1 + ob1) ----------------
__global__ void __launch_bounds__(256) head_gemv(
        const ushort* __restrict__ Hrelu, const float* __restrict__ ow1,
        const float* __restrict__ ob1, float* __restrict__ outp) {
    const int wave = threadIdx.x >> 6, lane = threadIdx.x & 63;
    const int row = blockIdx.x * 4 + wave;
    typedef ushort u16x8 __attribute__((ext_vector_type(8)));
    u16x8 hv = *(const u16x8*)&Hrelu[(size_t)row * HDIM + lane * 8];
    float4 w0 = *(const float4*)&ow1[lane * 8];
    float4 w1 = *(const float4*)&ow1[lane * 8 + 4];
    float s = bf2f(hv[0]) * w0.x + bf2f(hv[1]) * w0.y + bf2f(hv[2]) * w0.z +
              bf2f(hv[3]) * w0.w + bf2f(hv[4]) * w1.x + bf2f(hv[5]) * w1.y +
              bf2f(hv[6]) * w1.z + bf2f(hv[7]) * w1.w;
#pragma unroll
    for (int sh = 32; sh; sh >>= 1) s += __shfl_xor(s, sh, 64);
    if (lane == 0) outp[row] = 1.f / (1.f + __expf(-(s + ob1[0])));
}

extern "C" void kernel_launch(void* const* d_in, const int* in_sizes, int n_in,
                              void* d_out, int out_size, void* d_ws, size_t ws_size,
                              hipStream_t stream) {
    const float* x    = (const float*)d_in[0];
    const float* h    = (const float*)d_in[1];
    const float* c    = (const float*)d_in[2];
    const float* aw0  = (const float*)d_in[3];
    const float* ab0  = (const float*)d_in[4];
    const float* aw1  = (const float*)d_in[5];
    const float* ab1  = (const float*)d_in[6];
    const float* w_ih = (const float*)d_in[7];
    const float* b_ih = (const float*)d_in[8];
    const float* w_hh = (const float*)d_in[9];
    const float* b_hh = (const float*)d_in[10];
    const float* ow0  = (const float*)d_in[11];
    const float* ob0  = (const float*)d_in[12];
    const float* ow1  = (const float*)d_in[13];
    const float* ob1  = (const float*)d_in[14];

    char* ws = (char*)d_ws;
    ushort* xh     = (ushort*)(ws + 0);           // 8192*768*2  = 12582912
    ushort* a0     = (ushort*)(ws + 12582912);    // 8192*256*2  = 4194304
    float*  logits = (float*) (ws + 16777216);    // 8192*256*4  = 8388608
    ushort* hrelu  = (ushort*)(ws + 16777216);    // aliases logits (dead after softmax)
    ushort* hbf    = (ushort*)(ws + 25165824);    // 8192*512*2  = 8388608
    ushort* baw0   = (ushort*)(ws + 33554432);    // 256*768*2   = 393216
    ushort* baw1   = (ushort*)(ws + 33947648);    // 256*256*2   = 131072
    ushort* wcat   = (ushort*)(ws + 34078720);    // 2048*768*2  = 3145728
    ushort* bow0   = (ushort*)(ws + 37224448);    // 512*512*2   = 524288

    float* outv    = (float*)d_out;               // [8192]
    float* h_out   = outv + 8192;                 // [8192,512]
    float* c_out   = outv + 4202496;              // [8192,512]
    float* attn_o  = outv + 8396800;              // [8192,256]

    prep_kernel<<<8192, 256, 0, stream>>>(x, h, aw0, aw1, w_ih, w_hh, ow0,
                                          xh, baw0, baw1, wcat, bow0);
    // a0 = relu(xh @ aw0^T + ab0)         M=8192 N=256 K=768 -> 64x4 = 256 blocks
    staged_gemm<1, 2><<<256, 256, 0, stream>>>(xh, baw0, ab0, a0, KCAT, IDIM);
    // logits = a0 @ aw1^T + ab1           M=8192 N=256 K=256 -> 64x4 = 256 blocks
    staged_gemm<0, 2><<<256, 256, 0, stream>>>(a0, baw1, ab1, logits, IDIM, IDIM);
    attn_softmax<<<2048, 256, 0, stream>>>(logits, x, attn_o, xh);
    // fused LSTM gates                    M=8192 N=2048 K=768 -> 32x8 = 256 blocks (16-wave)
    gates_staged<<<256, 1024, 0, stream>>>(xh, wcat, b_ih, b_hh, c,
                                           h_out, c_out, hbf);
    // hrelu = relu(h_new @ ow0^T + ob0)   M=8192 N=512 K=512 -> 64x4 = 256 blocks
    staged_gemm<1, 4><<<256, 256, 0, stream>>>(hbf, bow0, ob0, hrelu, HDIM, HDIM);
    head_gemv<<<2048, 256, 0, stream>>>(hrelu, ow1, ob1, outv);
}